// Round 1
// 392.673 us; speedup vs baseline: 1.1079x; 1.1079x over previous
//
#include <hip/hip_runtime.h>

typedef __bf16 bf16_t;
typedef bf16_t bf16x8 __attribute__((ext_vector_type(8)));
typedef bf16_t bf16x4 __attribute__((ext_vector_type(4)));
typedef float f32x4 __attribute__((ext_vector_type(4)));

#define BATCH 4
#define SEQ 4096
#define EMBED 512
#define MTOT (BATCH * SEQ)
#define NSPLIT 2
#define KT (SEQ / NSPLIT)     // 2048 keys per block
#define BC 32
#define FITERS (KT / BC)      // 64

__device__ float  Lacc_g[MTOT];         // row sum-of-exp accumulator
__device__ bf16_t Wbf_g[EMBED * EMBED]; // W pre-converted to bf16

// async global->LDS, 16 B per lane; lds base must be wave-uniform
__device__ __forceinline__ void async_copy16(const bf16_t* g, bf16_t* l) {
    __builtin_amdgcn_global_load_lds(
        (const __attribute__((address_space(1))) unsigned int*)g,
        (__attribute__((address_space(3))) unsigned int*)l, 16, 0, 0);
}

// ---------------------------------------------------------------------------
// Stage 0: W fp32 -> bf16 once
// ---------------------------------------------------------------------------
__global__ __launch_bounds__(256) void cvt_w_kernel(const float* __restrict__ W) {
    const int i = (blockIdx.x * 256 + threadIdx.x) * 4;
    float4 v = *(const float4*)&W[i];
    bf16x4 o;
    o[0] = (bf16_t)v.x; o[1] = (bf16_t)v.y; o[2] = (bf16_t)v.z; o[3] = (bf16_t)v.w;
    *(bf16x4*)&Wbf_g[i] = o;
}

// ---------------------------------------------------------------------------
// Stage 1: q = cos(x + theta) @ W^T + b  (M=16384, N=512, K=512).
// Writes kperm: MFMA-fragment-major layout. Per batch, per 32-row tile t,
// fragment f = kt*16 + kf (kt = (row%32)>>4, kf = dim>>5) is a contiguous
// 512-element chunk in exact A/B-frag lane order:
//   elem(row r32, dim d) at  t*16384 + f*512 + ((d>>3)&3)*128 + (r32&15)*8 + (d&7)
// so flash's ds_read/global_load for a frag is base + lane*16B (conflict-free,
// fully coalesced, and DMA-compatible: linear LDS dest). Also writes qt
// (per-batch transpose for V reads) and zeroes Lacc_g.
// ---------------------------------------------------------------------------
__global__ __launch_bounds__(256, 2) void gemm_q_kernel(
    const float* __restrict__ x, const float* __restrict__ theta,
    const float* __restrict__ bias,
    bf16_t* __restrict__ kperm, bf16_t* __restrict__ qt)
{
    __shared__ alignas(16) bf16_t As[32][40];
    __shared__ alignas(16) bf16_t Ws[512][40];
    __shared__ float th[64];

    const int t    = threadIdx.x;
    const int m0   = blockIdx.x * 32;
    const int lane = t & 63;
    const int wave = t >> 6;
    const int l15  = lane & 15;
    const int quad = lane >> 4;

    if (t < 64) th[t] = theta[t];
    if (blockIdx.x < 16)
        ((float4*)Lacc_g)[blockIdx.x * 256 + t] = make_float4(0.f, 0.f, 0.f, 0.f);

    f32x4 acc[2][8];
#pragma unroll
    for (int m = 0; m < 2; ++m)
#pragma unroll
        for (int n = 0; n < 8; ++n) acc[m][n] = (f32x4){0.f, 0.f, 0.f, 0.f};

    const int arow = t >> 3;          // 0..31
    const int aseg = t & 7;           // 0..7 (4 floats)

    for (int kk = 0; kk < 16; ++kk) {
        const int k0 = kk * 32;
        __syncthreads();
        {   // A = bf16(cos(x+theta)): 32 x 32
            float4 xv = *(const float4*)&x[(m0 + arow) * 512 + k0 + aseg * 4];
            bf16x4 av;
            av[0] = (bf16_t)__cosf(xv.x + th[(k0 + aseg * 4 + 0) & 63]);
            av[1] = (bf16_t)__cosf(xv.y + th[(k0 + aseg * 4 + 1) & 63]);
            av[2] = (bf16_t)__cosf(xv.z + th[(k0 + aseg * 4 + 2) & 63]);
            av[3] = (bf16_t)__cosf(xv.w + th[(k0 + aseg * 4 + 3) & 63]);
            *(bf16x4*)&As[arow][aseg * 4] = av;
        }
        // W (already bf16): 512 rows x 32 k
#pragma unroll
        for (int cc = 0; cc < 8; ++cc) {
            int idx = t + 256 * cc;       // 0..2047
            int row = idx >> 2;           // 0..511
            int seg = idx & 3;            // 8 shorts each
            *(bf16x8*)&Ws[row][seg * 8] =
                *(const bf16x8*)&Wbf_g[row * 512 + k0 + seg * 8];
        }
        __syncthreads();
        bf16x8 af[2];
#pragma unroll
        for (int m = 0; m < 2; ++m)
            af[m] = *(const bf16x8*)&As[m * 16 + l15][quad * 8];
#pragma unroll
        for (int n = 0; n < 8; ++n) {
            bf16x8 bfr = *(const bf16x8*)&Ws[wave * 128 + n * 16 + l15][quad * 8];
#pragma unroll
            for (int m = 0; m < 2; ++m)
                acc[m][n] = __builtin_amdgcn_mfma_f32_16x16x32_bf16(af[m], bfr, acc[m][n], 0, 0, 0);
        }
    }

#pragma unroll
    for (int n = 0; n < 8; ++n) {
        const int col = wave * 128 + n * 16 + l15;
        const float bv = bias[col];
        const int kf = col >> 5;          // dim fragment
        const int qk = (col >> 3) & 3;    // quad-of-dim within 32
        const int jj = col & 7;
#pragma unroll
        for (int m = 0; m < 2; ++m) {
            const int row0 = m0 + m * 16 + quad * 4;   // 4 consecutive rows
            const int b    = row0 >> 12;
            const int i0   = row0 & 4095;
            const int tile = i0 >> 5;                  // kt = m within tile
            const size_t kb = (size_t)b * (SEQ * EMBED) + (size_t)tile * 16384
                            + (size_t)(m * 16 + kf) * 512 + qk * 128
                            + (quad * 4) * 8 + jj;
            bf16x4 pack;
#pragma unroll
            for (int r = 0; r < 4; ++r) {
                bf16_t qv = (bf16_t)(acc[m][n][r] + bv);
                kperm[kb + r * 8] = qv;                // l15k = quad*4 + r
                pack[r] = qv;
            }
            *(bf16x4*)&qt[((size_t)(b * 512 + col) << 12) + i0] = pack;
        }
    }
}

// ---------------------------------------------------------------------------
// Stage 2: attention, software-pipelined K-loop, ONE barrier per iter.
// Br=64, Bc=32, KV-split 2 -> grid 512 (= exactly 2 blocks/CU; each XCD owns
// one (batch, K-half): 4 MB working set = its L2). Frag-major LDS:
//   Ks[buf][frag*512 + lane*8]  -- K-tile as 32 x 1KB A-frags (DMA linear,
//                                  ds_read_b128 at base+lane*16: 0 conflicts)
//   Ps[buf][mt*512 + lane*8]    -- P as 4 A-frags, wave writes own frag mt=wave
// Per body(it): issue DMA K(it+1), V(it-1) global loads, QK(it) (A=K frags,
// B=Q regs), exp -> Ps[cbuf], PV(it-1) (A=P frags, B=V regs).
// ---------------------------------------------------------------------------
__global__ __launch_bounds__(256, 2) void flash_kernel(
    const bf16_t* __restrict__ kp, const bf16_t* __restrict__ qt,
    float* __restrict__ out)
{
    __shared__ alignas(16) bf16_t Ks[2][32 * 512];   // 65536 B, frag-major
    __shared__ alignas(16) bf16_t Ps[2][4 * 512];    //  8192 B, frag-major

    const int t    = threadIdx.x;
    const int lane = t & 63;
    const int wave = t >> 6;
    const int l15  = lane & 15;
    const int quad = lane >> 4;

    // XCD-aware remap: 512 blocks, xcd = L&7 owns one (batch, ksplit) group
    const int L      = blockIdx.x;            // 0..511
    const int g      = L & 7;                 // 0..7
    const int qtile  = L >> 3;                // 0..63
    const int batch  = g >> 1;
    const int ksplit = g & 1;

    const int q0     = qtile * 64;
    const int kbase  = ksplit * KT;
    const int ktile0 = kbase >> 5;            // first 32-key tile index
    const bf16_t* kpb = kp + (size_t)batch * SEQ * EMBED;
    const bf16_t* qtb = qt + (size_t)batch * EMBED * SEQ;

    // stage K-tile 0: 32 frags x 1 KB, 8 per wave, linear DMA
#pragma unroll
    for (int cc = 0; cc < 8; ++cc) {
        const int f = cc * 4 + wave;
        async_copy16(&kpb[(size_t)ktile0 * 16384 + f * 512 + lane * 8],
                     &Ks[0][f * 512]);
    }

    // Q B-frags (wave owns q-rows q0+wave*16..+15), read from frag-major kperm
    bf16x8 bQ[16];
    {
        const size_t qb = (size_t)(qtile * 2 + (wave >> 1)) * 16384
                        + (size_t)(wave & 1) * 16 * 512;
#pragma unroll
        for (int kf = 0; kf < 16; ++kf)
            bQ[kf] = *(const bf16x8*)&kpb[qb + kf * 512 + quad * 128 + l15 * 8];
    }

    f32x4 O[4][8];   // PV e-split: wave owns e-range wave*128 (8 n-tiles x 16)
#pragma unroll
    for (int m = 0; m < 4; ++m)
#pragma unroll
        for (int n = 0; n < 8; ++n) O[m][n] = (f32x4){0.f, 0.f, 0.f, 0.f};
    float lpart = 0.f;

    for (int it = 0; it < FITERS; ++it) {
        const int cbuf = it & 1;
        const int pbuf = cbuf ^ 1;
        __syncthreads();   // DMA K(it) landed; Ps(it-1) visible; Ks[pbuf] reads done
        // ---- issue DMA K(it+1) into Ks[pbuf] (waited at next barrier) ----
        if (it + 1 < FITERS) {
#pragma unroll
            for (int cc = 0; cc < 8; ++cc) {
                const int f = cc * 4 + wave;
                async_copy16(&kpb[(size_t)(ktile0 + it + 1) * 16384 + f * 512 + lane * 8],
                             &Ks[pbuf][f * 512]);
            }
        }
        // ---- V(it-1) global loads (latency hidden behind QK below) ----
        bf16x8 bv[8];
        if (it) {
            const int kv = kbase + (it - 1) * BC;
#pragma unroll
            for (int n = 0; n < 8; ++n)
                bv[n] = *(const bf16x8*)&qtb[(size_t)(wave * 128 + n * 16 + l15) * 4096
                                             + kv + quad * 8];
        }
        // ---- QK(it): S^T = K * Q^T, A=K frag (seq. lane*16 read), B=Q regs ----
        f32x4 s[2];
#pragma unroll
        for (int kt = 0; kt < 2; ++kt) {
            f32x4 a = (f32x4){0.f, 0.f, 0.f, 0.f};
#pragma unroll
            for (int kf = 0; kf < 16; ++kf) {
                bf16x8 ak = *(const bf16x8*)&Ks[cbuf][(kt * 16 + kf) * 512 + lane * 8];
                a = __builtin_amdgcn_mfma_f32_16x16x32_bf16(ak, bQ[kf], a, 0, 0, 0);
            }
            s[kt] = a;
        }
        // ---- P = exp(s/8): lane holds P[q=wave*16+l15][key=kt*16+quad*4+r] ----
        // write to frag mt=wave of Ps: elem offset (k>>3)*128 + l15*8 + (k&7)
#pragma unroll
        for (int kt = 0; kt < 2; ++kt) {
            bf16x4 pk;
#pragma unroll
            for (int r = 0; r < 4; ++r) {
                bf16_t pb = (bf16_t)__expf(s[kt][r] * 0.125f);
                lpart += (float)pb;
                pk[r] = pb;
            }
            *(bf16x4*)&Ps[cbuf][wave * 512 + (kt * 2 + (quad >> 1)) * 128
                                + l15 * 8 + (quad & 1) * 4] = pk;
        }
        // ---- PV(it-1): A=P frags (seq. lane*16 read), B=bv ----
        if (it) {
            bf16x8 pa[4];
#pragma unroll
            for (int mt = 0; mt < 4; ++mt)
                pa[mt] = *(const bf16x8*)&Ps[pbuf][mt * 512 + lane * 8];
#pragma unroll
            for (int n = 0; n < 8; ++n)
#pragma unroll
                for (int mt = 0; mt < 4; ++mt)
                    O[mt][n] = __builtin_amdgcn_mfma_f32_16x16x32_bf16(pa[mt], bv[n], O[mt][n], 0, 0, 0);
        }
    }
    // ---- final PV(FITERS-1) ----
    __syncthreads();
    {
        const int pbuf = (FITERS - 1) & 1;
        const int kv = kbase + (FITERS - 1) * BC;
        bf16x8 bv[8];
#pragma unroll
        for (int n = 0; n < 8; ++n)
            bv[n] = *(const bf16x8*)&qtb[(size_t)(wave * 128 + n * 16 + l15) * 4096
                                         + kv + quad * 8];
        bf16x8 pa[4];
#pragma unroll
        for (int mt = 0; mt < 4; ++mt)
            pa[mt] = *(const bf16x8*)&Ps[pbuf][mt * 512 + lane * 8];
#pragma unroll
        for (int n = 0; n < 8; ++n)
#pragma unroll
            for (int mt = 0; mt < 4; ++mt)
                O[mt][n] = __builtin_amdgcn_mfma_f32_16x16x32_bf16(pa[mt], bv[n], O[mt][n], 0, 0, 0);
    }

    // ---- row exp-sums: row = wave*16+l15, keys spread over quad ----
    {
        float ls = lpart;
        ls += __shfl_xor(ls, 16);
        ls += __shfl_xor(ls, 32);
        if (quad == 0)
            atomicAdd(&Lacc_g[batch * SEQ + q0 + wave * 16 + l15], ls);
    }
    // ---- unnormalized O -> out; D: row=quad*4+r (q-row), col=l15 (e) ----
#pragma unroll
    for (int mt = 0; mt < 4; ++mt)
#pragma unroll
        for (int r = 0; r < 4; ++r) {
            const size_t row = (size_t)batch * SEQ + q0 + mt * 16 + quad * 4 + r;
#pragma unroll
            for (int n = 0; n < 8; ++n)
                atomicAdd(&out[row * 512 + wave * 128 + n * 16 + l15], O[mt][n][r]);
        }
}

// out[row][e] /= Lacc_g[row]
__global__ __launch_bounds__(256) void norm_kernel(float* __restrict__ out)
{
    const int idx = blockIdx.x * 256 + threadIdx.x;   // float4 index
    float4 v = ((float4*)out)[idx];
    const float inv = 1.0f / Lacc_g[idx >> 7];
    v.x *= inv; v.y *= inv; v.z *= inv; v.w *= inv;
    ((float4*)out)[idx] = v;
}

extern "C" void kernel_launch(void* const* d_in, const int* in_sizes, int n_in,
                              void* d_out, int out_size, void* d_ws, size_t ws_size,
                              hipStream_t stream) {
    const float* x     = (const float*)d_in[0];
    const float* theta = (const float*)d_in[1];
    const float* W     = (const float*)d_in[2];
    const float* bias  = (const float*)d_in[3];
    float* out    = (float*)d_out;
    bf16_t* kperm = (bf16_t*)d_ws;                      // [4][128 tiles][32 frags][512] bf16
    bf16_t* qt    = kperm + (size_t)MTOT * EMBED;       // [4][512][4096] bf16

    hipMemsetAsync(out, 0, (size_t)MTOT * EMBED * sizeof(float), stream);

    cvt_w_kernel<<<dim3(EMBED * EMBED / 4 / 256), dim3(256), 0, stream>>>(W);

    gemm_q_kernel<<<dim3(MTOT / 32), dim3(256), 0, stream>>>(x, theta, bias, kperm, qt);

    flash_kernel<<<dim3(64 * BATCH * NSPLIT), dim3(256), 0, stream>>>(kperm, qt, out);

    norm_kernel<<<dim3(MTOT * EMBED / 4 / 256), dim3(256), 0, stream>>>(out);
}